// Round 2
// 174.717 us; speedup vs baseline: 1.0718x; 1.0718x over previous
//
#include <hip/hip_runtime.h>
#include <math.h>

#define DM   1024
#define DS   64
#define BATCH 8
#define SEQ  2048
#define CL   32          // chunk length
#define NC   64          // number of chunks (SEQ/CL)

typedef __bf16 bf16x8 __attribute__((ext_vector_type(8)));
typedef float  f32x4  __attribute__((ext_vector_type(4)));

#if __has_builtin(__builtin_amdgcn_exp2f)
#define EXP2(v) __builtin_amdgcn_exp2f(v)
#else
#define EXP2(v) __expf(0.69314718056f * (v))
#endif

// ---------------------------------------------------------------------------
// Kernel W: pre-convert W_delta|W_Bp|W_Cp into packed bf16, K-tiled:
// Wp[(kt*192 + n)*32 + kk], k = kt*32+kk.  A 64-K block kb = contiguous
// 24 KB at Wp + kb*12288 elements.  (proven)
// ---------------------------------------------------------------------------
__global__ __launch_bounds__(256) void wconv_kernel(
    const float* __restrict__ Wd, const float* __restrict__ Wb,
    const float* __restrict__ Wc, __bf16* __restrict__ Wp)
{
    int idx = blockIdx.x * 256 + threadIdx.x;   // n*1024 + k
    int k  = idx & 1023;
    int n  = idx >> 10;                          // 0..191
    const float* W = (n < 64) ? Wd : (n < 128 ? Wb : Wc);
    float v = W[(size_t)(n & 63) * DM + k];
    int kt = k >> 5, kk = k & 31;
    Wp[((size_t)kt * 192 + n) * 32 + kk] = (__bf16)v;
}

// ---------------------------------------------------------------------------
// Kernel A+B fused: projection (v7 core) + pass1 local scan.  (proven,
// byte-identical to the 51.7us dispatch from the 186us session)
// ---------------------------------------------------------------------------
__global__ __launch_bounds__(256, 2) void projp1_full(
    const float* __restrict__ x, const __bf16* __restrict__ Wp,
    const float* __restrict__ bd, const float* __restrict__ bb,
    const float* __restrict__ bc, const float* __restrict__ A_log,
    float* __restrict__ delta_g, float* __restrict__ u_g,
    float* __restrict__ ct_g,
    float* __restrict__ E, float* __restrict__ Dsum)
{
    __shared__ __bf16 sB[2][12288];              // 2 x 24 KB
    __shared__ __bf16 sA[2][32 * 72];            // 2 x 4.5 KB
    __shared__ float  s_d[CL * 64];              // 8 KB
    __shared__ float  s_u[CL * 64];              // 8 KB

    const int tid  = threadIdx.x;
    const int row0 = blockIdx.x * 32;

    const int lane = tid & 63, wv = tid >> 6;
    const int l15  = lane & 15, quad = lane >> 4;
    const int nbase = wv * 48;                   // wave's N window

    const int am = tid >> 3;                     // staging row 0..31
    const int ak = tid & 7;                      // 8-float k-group 0..7
    const float* xga = x + (size_t)(row0 + am) * DM + ak * 8;

    f32x4 acc[2][3];
    #pragma unroll
    for (int mt = 0; mt < 2; ++mt)
        #pragma unroll
        for (int nt = 0; nt < 3; ++nt)
            acc[mt][nt] = (f32x4){0.f, 0.f, 0.f, 0.f};

    float4 areg[2];

#if __has_builtin(__builtin_amdgcn_global_load_lds)
    #define LOADB(kb, bi) do {                                                \
        _Pragma("unroll")                                                     \
        for (int it = 0; it < 6; ++it) {                                      \
            const __bf16* gsrc =                                              \
                Wp + (size_t)(kb) * 12288 + (tid + it * 256) * 8;             \
            __bf16* ldst = &sB[bi][(tid + it * 256) * 8];                     \
            __builtin_amdgcn_global_load_lds(                                 \
                (const __attribute__((address_space(1))) void*)gsrc,          \
                (__attribute__((address_space(3))) void*)ldst, 16, 0, 0);     \
        }                                                                     \
    } while (0)
#else
    #define LOADB(kb, bi) do {                                                \
        _Pragma("unroll")                                                     \
        for (int it = 0; it < 6; ++it) {                                      \
            uint4 t = *(const uint4*)(                                        \
                Wp + (size_t)(kb) * 12288 + (tid + it * 256) * 8);            \
            *(uint4*)&sB[bi][(tid + it * 256) * 8] = t;                       \
        }                                                                     \
    } while (0)
#endif
    #define LOADA(kb) do {                                                    \
        areg[0] = *(const float4*)(xga + (kb) * 64);                          \
        areg[1] = *(const float4*)(xga + (kb) * 64 + 4);                      \
    } while (0)
    #define STAGEA(bi) do {                                                   \
        bf16x8 hv = {(__bf16)areg[0].x, (__bf16)areg[0].y,                    \
                     (__bf16)areg[0].z, (__bf16)areg[0].w,                    \
                     (__bf16)areg[1].x, (__bf16)areg[1].y,                    \
                     (__bf16)areg[1].z, (__bf16)areg[1].w};                   \
        *(bf16x8*)&sA[bi][am * 72 + ak * 8] = hv;                             \
    } while (0)
    #define COMPUTE(bi) do {                                                  \
        _Pragma("unroll")                                                     \
        for (int s = 0; s < 2; ++s) {                                         \
            bf16x8 af[2];                                                     \
            _Pragma("unroll")                                                 \
            for (int mt = 0; mt < 2; ++mt)                                    \
                af[mt] = *(const bf16x8*)                                     \
                    &sA[bi][(mt * 16 + l15) * 72 + s * 32 + quad * 8];        \
            _Pragma("unroll")                                                 \
            for (int nt = 0; nt < 3; ++nt) {                                  \
                bf16x8 bv = *(const bf16x8*)                                  \
                    &sB[bi][s * 6144 + (nbase + nt * 16 + l15) * 32           \
                            + quad * 8];                                      \
                _Pragma("unroll")                                             \
                for (int mt = 0; mt < 2; ++mt)                                \
                    acc[mt][nt] = __builtin_amdgcn_mfma_f32_16x16x32_bf16(    \
                        af[mt], bv, acc[mt][nt], 0, 0, 0);                    \
            }                                                                 \
        }                                                                     \
    } while (0)

    LOADB(0, 0);
    LOADA(0);
    STAGEA(0);
    __syncthreads();                             // drains vmcnt before use

    int buf = 0;
    for (int kb = 0; kb < 16; ++kb) {
        if (kb < 15) {
            LOADB(kb + 1, buf ^ 1);              // async global->LDS
            LOADA(kb + 1);
        }
        COMPUTE(buf);
        if (kb < 15) STAGEA(buf ^ 1);
        __syncthreads();                         // one barrier per iter
        buf ^= 1;
    }
    #undef LOADB
    #undef LOADA
    #undef STAGEA
    #undef COMPUTE

    // epilogue: bias + activations; store global AND stage delta/u in LDS
    #pragma unroll
    for (int nt = 0; nt < 3; ++nt) {
        int gn  = nbase + nt * 16 + l15;         // 0..191
        int mat = (nbase + nt * 16) >> 6;        // wave-uniform per nt
        int col = gn & 63;
        float bias = (mat == 0) ? bd[col] : (mat == 1 ? bb[col] : bc[col]);
        #pragma unroll
        for (int mt = 0; mt < 2; ++mt) {
            #pragma unroll
            for (int r = 0; r < 4; ++r) {
                int tl = mt * 16 + quad * 4 + r; // local t 0..31
                int m  = row0 + tl;
                float v = acc[mt][nt][r] + bias;
                if (mat == 0) {
                    float sp = (v > 20.f) ? v : __logf(1.f + __expf(v));
                    delta_g[(size_t)m * DS + col] = sp;
                    s_d[tl * 64 + col] = sp;
                } else if (mat == 1) {
                    float uu = v * x[(size_t)m * DM + col];
                    u_g[(size_t)m * DS + col] = uu;
                    s_u[tl * 64 + col] = uu;
                } else {
                    ct_g[(size_t)m * DS + col] = v;
                }
            }
        }
    }
    __syncthreads();

    // ---- fused pass1: local chunk scan from h=0 ----
    const int bidx = row0 >> 11;                 // batch  (row0/2048)
    const int cidx = (row0 >> 5) & 63;           // chunk  ((row0/32)%64)
    const int si = tid & 63;
    const int sj = tid >> 6;

    float alog[16];
    {
        const float4* ar = (const float4*)(A_log + si * 64 + sj * 16);
        #pragma unroll
        for (int qq = 0; qq < 4; ++qq) {
            float4 v = ar[qq];
            alog[4*qq+0] = v.x * 1.44269504f; alog[4*qq+1] = v.y * 1.44269504f;
            alog[4*qq+2] = v.z * 1.44269504f; alog[4*qq+3] = v.w * 1.44269504f;
        }
    }

    float h[16];
    #pragma unroll
    for (int k = 0; k < 16; ++k) h[k] = 0.f;
    float dsum = 0.f;

    for (int t = 0; t < CL; ++t) {
        float d = s_d[t * 64 + si];
        dsum += d;
        const float* up = s_u + t * 64 + sj * 16;
        #pragma unroll
        for (int k = 0; k < 16; ++k)
            h[k] = EXP2(alog[k] * d) * h[k] + up[k];
    }

    float* eo = E + (((size_t)cidx * BATCH + bidx) * 64 + si) * 64 + sj * 16;
    #pragma unroll
    for (int qq = 0; qq < 4; ++qq)
        ((float4*)eo)[qq] = make_float4(h[4*qq], h[4*qq+1], h[4*qq+2], h[4*qq+3]);
    if (sj == 0) Dsum[((size_t)cidx * BATCH + bidx) * 64 + si] = dsum;
}

// ---------------------------------------------------------------------------
// Pipelined affine-scan combine over records n0..n1-1 laid out as
// Db[(n*BATCH + b)*64 + i] / Eb[((n*BATCH + b)*64 + i)*64 + jg*16].
// 1-deep prefetch so the next record's L2/L3 latency hides under the
// current record's 16 exp2+fma chain.
// ---------------------------------------------------------------------------
__device__ __forceinline__ void scan_range(
    const float* __restrict__ Eb, const float* __restrict__ Db,
    int n0, int n1, int bb_, int i_, int jg_,
    const float* __restrict__ alog, float* __restrict__ h)
{
    if (n0 >= n1) return;
    size_t idx = ((size_t)n0 * BATCH + bb_) * 64 + i_;
    float dsA = Db[idx];
    const float4* ep = (const float4*)(Eb + idx * 64 + jg_ * 16);
    float4 e0 = ep[0], e1 = ep[1], e2 = ep[2], e3 = ep[3];
    for (int n = n0; n < n1; ++n) {
        float dsN = 0.f;
        float4 f0 = make_float4(0.f,0.f,0.f,0.f), f1 = f0, f2 = f0, f3 = f0;
        if (n + 1 < n1) {
            size_t idx2 = ((size_t)(n + 1) * BATCH + bb_) * 64 + i_;
            dsN = Db[idx2];
            const float4* fp = (const float4*)(Eb + idx2 * 64 + jg_ * 16);
            f0 = fp[0]; f1 = fp[1]; f2 = fp[2]; f3 = fp[3];
        }
        float ev[16] = {e0.x,e0.y,e0.z,e0.w, e1.x,e1.y,e1.z,e1.w,
                        e2.x,e2.y,e2.z,e2.w, e3.x,e3.y,e3.z,e3.w};
        #pragma unroll
        for (int k = 0; k < 16; ++k)
            h[k] = EXP2(alog[k] * dsA) * h[k] + ev[k];
        dsA = dsN; e0 = f0; e1 = f1; e2 = f2; e3 = f3;
    }
}

// ---------------------------------------------------------------------------
// Kernel G: group composites.  Block (g2,b2) folds chunks 8*g2..8*g2+7 into
// (Eg, Dg): decay exponents add (Dg = sum Dsum), Eg = 8-step scan from 0.
// 64 blocks, ~8 prefetched combines each.
// ---------------------------------------------------------------------------
__global__ __launch_bounds__(256) void group_kernel(
    const float* __restrict__ E, const float* __restrict__ Dsum,
    const float* __restrict__ A_log,
    float* __restrict__ Eg, float* __restrict__ Dg)
{
    const int g2 = blockIdx.x >> 3, b2 = blockIdx.x & 7;
    const int tid = threadIdx.x;
    const int i  = tid >> 2;                          // 0..63
    const int jg = tid & 3;                           // 0..3

    float alog[16];
    {
        const float4* ar = (const float4*)(A_log + i * 64 + jg * 16);
        #pragma unroll
        for (int qq = 0; qq < 4; ++qq) {
            float4 v = ar[qq];
            alog[4*qq+0] = v.x * 1.44269504f; alog[4*qq+1] = v.y * 1.44269504f;
            alog[4*qq+2] = v.z * 1.44269504f; alog[4*qq+3] = v.w * 1.44269504f;
        }
    }

    float hg[16];
    #pragma unroll
    for (int k = 0; k < 16; ++k) hg[k] = 0.f;
    scan_range(E, Dsum, g2 * 8, g2 * 8 + 8, b2, i, jg, alog, hg);

    float4* ego = (float4*)(Eg + (((size_t)g2 * BATCH + b2) * 64 + i) * 64 + jg * 16);
    ego[0] = make_float4(hg[0],  hg[1],  hg[2],  hg[3]);
    ego[1] = make_float4(hg[4],  hg[5],  hg[6],  hg[7]);
    ego[2] = make_float4(hg[8],  hg[9],  hg[10], hg[11]);
    ego[3] = make_float4(hg[12], hg[13], hg[14], hg[15]);
    if (jg == 0) {
        float Dacc = 0.f;
        #pragma unroll
        for (int q = 0; q < 8; ++q)
            Dacc += Dsum[((size_t)(g2 * 8 + q) * BATCH + b2) * 64 + i];
        Dg[((size_t)g2 * BATCH + b2) * 64 + i] = Dacc;
    }
}

// ---------------------------------------------------------------------------
// Kernel C+D fused: each block (c,b) computes its OWN incoming state via the
// TWO-LEVEL prefix (<=7 group combines + <=7 chunk combines, prefetched),
// then replays the chunk and emits y.  Replay identical to proven version.
// ---------------------------------------------------------------------------
__global__ __launch_bounds__(256) void pass23_kernel(
    const float* __restrict__ delta_g, const float* __restrict__ u_g,
    const float* __restrict__ ct_g, const float* __restrict__ A_log,
    const float* __restrict__ E, const float* __restrict__ Dsum,
    const float* __restrict__ Eg, const float* __restrict__ Dg,
    float* __restrict__ out)
{
    __shared__ float s_d[CL * 64];
    __shared__ float s_u[CL * 64];
    __shared__ float s_c[CL * 64];

    const int c = blockIdx.x, b = blockIdx.y, tid = threadIdx.x;
    const int t0 = c * CL;

    const float4* dg = (const float4*)(delta_g + ((size_t)b * SEQ + t0) * DS);
    const float4* ug = (const float4*)(u_g     + ((size_t)b * SEQ + t0) * DS);
    const float4* cg = (const float4*)(ct_g    + ((size_t)b * SEQ + t0) * DS);
    #pragma unroll
    for (int it = 0; it < (CL * 64 / 4) / 256; ++it) {
        int f = tid + it * 256;
        ((float4*)s_d)[f] = dg[f];
        ((float4*)s_u)[f] = ug[f];
        ((float4*)s_c)[f] = cg[f];
    }

    const int i  = tid >> 2;                          // 0..63
    const int jg = tid & 3;                           // 0..3

    float alog[16];
    {
        const float4* ar = (const float4*)(A_log + i * 64 + jg * 16);
        #pragma unroll
        for (int qq = 0; qq < 4; ++qq) {
            float4 v = ar[qq];
            alog[4*qq+0] = v.x * 1.44269504f; alog[4*qq+1] = v.y * 1.44269504f;
            alog[4*qq+2] = v.z * 1.44269504f; alog[4*qq+3] = v.w * 1.44269504f;
        }
    }

    // ---- two-level prefix: groups 0..g-1, then chunks 8g..c-1 ----
    float h[16];
    #pragma unroll
    for (int k = 0; k < 16; ++k) h[k] = 0.f;
    const int g = c >> 3;
    scan_range(Eg, Dg, 0, g, b, i, jg, alog, h);
    scan_range(E, Dsum, g * 8, c, b, i, jg, alog, h);
    __syncthreads();

    // ---- replay + output (proven) ----
    for (int t = 0; t < CL; ++t) {
        float d = s_d[t * 64 + i];
        const float* up  = s_u + t * 64 + jg * 16;
        const float* cp2 = s_c + t * 64 + jg * 16;
        float part = 0.f;
        #pragma unroll
        for (int k = 0; k < 16; ++k) {
            h[k] = EXP2(alog[k] * d) * h[k] + up[k];
            part += cp2[k] * h[k];
        }
        part += __shfl_xor(part, 1);
        part += __shfl_xor(part, 2);
        if (jg == 0)
            out[((size_t)b * SEQ + t0 + t) * DS + i] = part;
    }
}

// ---------------------------------------------------------------------------
// Inputs: 0:x 1..6:(cog/beh/env dead) 7:W_delta 8:b_delta 9:W_Bp 10:b_Bp
//         11:W_Cp 12:b_Cp 13:A_log
// ---------------------------------------------------------------------------
extern "C" void kernel_launch(void* const* d_in, const int* in_sizes, int n_in,
                              void* d_out, int out_size, void* d_ws, size_t ws_size,
                              hipStream_t stream)
{
    (void)in_sizes; (void)n_in; (void)out_size; (void)ws_size;
    const float* x     = (const float*)d_in[0];
    const float* Wd    = (const float*)d_in[7];
    const float* bd    = (const float*)d_in[8];
    const float* Wb    = (const float*)d_in[9];
    const float* bb    = (const float*)d_in[10];
    const float* Wc    = (const float*)d_in[11];
    const float* bc    = (const float*)d_in[12];
    const float* A_log = (const float*)d_in[13];
    float* out = (float*)d_out;

    float* ws = (float*)d_ws;
    float* delta_g = ws;                       // 1,048,576 floats
    float* u_g     = ws + 1 * 1048576;         // 1,048,576
    float* ct_g    = ws + 2 * 1048576;         // 1,048,576
    float* E       = ws + 3 * 1048576;         // 2,097,152
    float* Dsum    = ws + 5242880;             // 32,768
    float* Eg      = ws + 5275648;             // 262,144
    float* Dg      = ws + 5537792;             // 4,096
    __bf16* Wp     = (__bf16*)(ws + 5541888);  // 196,608 bf16

    wconv_kernel<<<768, 256, 0, stream>>>(Wd, Wb, Wc, Wp);
    projp1_full<<<512, 256, 0, stream>>>(
        x, Wp, bd, bb, bc, A_log, delta_g, u_g, ct_g, E, Dsum);
    group_kernel<<<64, 256, 0, stream>>>(E, Dsum, A_log, Eg, Dg);
    pass23_kernel<<<dim3(NC, BATCH), 256, 0, stream>>>(
        delta_g, u_g, ct_g, A_log, E, Dsum, Eg, Dg, out);
}